// Round 10
// baseline (160.978 us; speedup 1.0000x reference)
//
#include <hip/hip_runtime.h>
#include <hip/hip_bf16.h>

// out[e] = relu(concat(x[src],x[dst]) @ W1 + b1) @ W2 + b2
// Phase 1: uv[n][0:256] = x[n]@W1[:256,:], uv[n][256:512] = x[n]@W1[256:,:] (bf16)
//   Stream GEMM, direct fp32 x: block owns 128 uv-cols; W1 slice in LDS
//   frag-major (64 KB, staged once, one barrier, zero-conflict ds_reads).
//   Waves free-run over 16-row chunks; A = 16 dense dwordx4 loads/chunk,
//   reg double-buffered, cvt bf16 in-reg. launch_bounds(256,1): allocator may
//   take ~200 VGPR (2 waves/SIMD = exactly our 2-blocks/CU residency).
// Phase 2: per-edge sum_k relu(uv[src][k]+uv[dst][256+k]+b1[k])*W2[k] + b2,
//   quarter-wave per edge, 2-edge unroll (8 gathers in flight).

typedef short short8 __attribute__((ext_vector_type(8)));
typedef float f32x4 __attribute__((ext_vector_type(4)));

#define DINC 256
#define NOUTC 512

__device__ inline unsigned short f2bf(float f) {   // RNE (cold path)
  union { float f; unsigned u; } c; c.f = f;
  unsigned u = c.u;
  return (unsigned short)((u + 0x7FFFu + ((u >> 16) & 1u)) >> 16);
}
__device__ inline float bf2f(unsigned short h) {
  union { unsigned u; float f; } c; c.u = ((unsigned)h) << 16;
  return c.f;
}
__device__ inline unsigned short fbf(float f) {    // fuses to v_cvt_pk_bf16_f32
  union { __hip_bfloat16 h; unsigned short u; } c;
  c.h = __float2bfloat16(f);
  return c.u;
}

// W1t frag-major: t = granule id in [0,16384): bn=t>>12, kt=(t>>9)&7,
// nf=(t>>6)&7, lane=t&63 -> col = bn*128+nf*16+(lane&15),
// k = kt*32+(lane>>4)*8+j.  W1'[k][col] = col<256 ? W1[k][col] : W1[256+k][col-256].
__global__ void w1t_kernel(const float* __restrict__ W1, unsigned short* __restrict__ W1t) {
  int t = blockIdx.x * 256 + threadIdx.x;           // 0..16383
  int lane = t & 63, nf = (t >> 6) & 7, kt = (t >> 9) & 7, bn = t >> 12;
  int col = bn * 128 + nf * 16 + (lane & 15);
  int k0 = kt * 32 + (lane >> 4) * 8;
  int off = (col >= 256) ? 256 : 0;
  int cs = col & 255;
  short8 v;
#pragma unroll
  for (int j = 0; j < 8; ++j)
    v[j] = (short)f2bf(W1[(size_t)(k0 + j + off) * DINC + cs]);
  *(short8*)(W1t + (size_t)t * 8) = v;
}

// 256 thr = 4 waves, 2 blocks/CU (LDS-limited), grid 512 persistent.
__global__ __launch_bounds__(256, 1) void uv_gemm(const float* __restrict__ x,
                                                  const unsigned short* __restrict__ W1t,
                                                  unsigned short* __restrict__ uv,
                                                  int Nn) {
  __shared__ unsigned short Bs[128 * DINC];          // 64 KB frag-major

  // XCD remap: the 4 bn-slices of the same rank co-resident on one XCD L2.
  int L = (blockIdx.x & 7) * (gridDim.x >> 3) + (blockIdx.x >> 3);
  int bn = L & 3, rank = L >> 2;

  int tid = threadIdx.x, lane = tid & 63, w = tid >> 6;
  int lr = lane & 15, kg = lane >> 4;

  // ---- stage B slice once (linear 64 KB copy, frag-major source) ----
  {
    const char* bsrc = (const char*)W1t + (size_t)bn * 65536;
#pragma unroll
    for (int i = 0; i < 16; ++i) {
      int o = i * 4096 + w * 1024;                   // wave-uniform base
      __builtin_amdgcn_global_load_lds(
          (const __attribute__((address_space(1))) void*)(bsrc + o + lane * 16),
          (__attribute__((address_space(3))) void*)((char*)Bs + o), 16, 0, 0);
    }
  }
  __syncthreads();                                   // the only barrier

  int nch = (Nn + 15) >> 4;                          // 6250
  int stream = rank * 4 + w;                         // 0..511
  const int S = 512;

  // A-chunk: 16 rows x K=256 fp32. Lane (lr,kg) reads row lr, cols kt*32+kg*8..+8
  // (2 dwordx4). Per instr: 4 kg-lanes cover 64B line halves -> pairwise dense.
#define LOADH(BUF, C)                                                          \
  {                                                                            \
    int row_ = (C) * 16 + lr;                                                  \
    if (row_ >= Nn) row_ = Nn - 1;                                             \
    const float4* xp_ = (const float4*)(x + (size_t)row_ * DINC + kg * 8);     \
    _Pragma("unroll")                                                          \
    for (int kt = 0; kt < 8; ++kt) {                                           \
      BUF[2 * kt]     = xp_[kt * 8];                                           \
      BUF[2 * kt + 1] = xp_[kt * 8 + 1];                                       \
    }                                                                          \
  }

#define CS(BUF, C)                                                             \
  {                                                                            \
    f32x4 acc[8] = {};                                                         \
    _Pragma("unroll")                                                          \
    for (int kt = 0; kt < 8; ++kt) {                                           \
      float4 f0 = BUF[2 * kt], f1 = BUF[2 * kt + 1];                           \
      short8 a;                                                                \
      a[0] = (short)fbf(f0.x); a[1] = (short)fbf(f0.y);                        \
      a[2] = (short)fbf(f0.z); a[3] = (short)fbf(f0.w);                        \
      a[4] = (short)fbf(f1.x); a[5] = (short)fbf(f1.y);                        \
      a[6] = (short)fbf(f1.z); a[7] = (short)fbf(f1.w);                        \
      _Pragma("unroll")                                                        \
      for (int nf = 0; nf < 8; ++nf) {                                         \
        short8 bf_ = *(const short8*)((char*)Bs + ((kt * 8 + nf) * 64 + lane) * 16); \
        acc[nf] = __builtin_amdgcn_mfma_f32_16x16x32_bf16(bf_, a,              \
                                                          acc[nf], 0, 0, 0);   \
      }                                                                        \
    }                                                                          \
    int row_ = (C) * 16 + lr;                                                  \
    if (row_ < Nn) {                                                           \
      unsigned short* orow_ = uv + (size_t)row_ * NOUTC + bn * 128 + kg * 4;   \
      _Pragma("unroll")                                                        \
      for (int nf = 0; nf < 8; ++nf) {                                         \
        ushort4 pk;                                                            \
        pk.x = fbf(acc[nf][0]); pk.y = fbf(acc[nf][1]);                        \
        pk.z = fbf(acc[nf][2]); pk.w = fbf(acc[nf][3]);                        \
        *(ushort4*)(orow_ + nf * 16) = pk;                                     \
      }                                                                        \
    }                                                                          \
  }

  float4 A0[16], A1[16];
  int c = stream;
  if (c < nch) {
    LOADH(A0, c);
    for (;;) {
      int c1 = c + S;
      if (c1 < nch) {
        LOADH(A1, c1);                               // next chunk under compute
        CS(A0, c);
        int c2 = c1 + S;
        if (c2 < nch) {
          LOADH(A0, c2);
          CS(A1, c1);
          c = c2;
        } else { CS(A1, c1); break; }
      } else { CS(A0, c); break; }
    }
  }
#undef LOADH
#undef CS
}

// Quarter-wave (16 lanes) per edge, 2-edge unroll: 8 gathers in flight.
__global__ __launch_bounds__(256) void edge_kernel(const int* __restrict__ eliW,
                                                   const unsigned short* __restrict__ uv,
                                                   const float* __restrict__ b1,
                                                   const float* __restrict__ W2,
                                                   const float* __restrict__ b2,
                                                   float* __restrict__ out, int E) {
  int tid = threadIdx.x;
  int ql = tid & 15;
  bool is64 = ((eliW[1] | eliW[3] | eliW[5] | eliW[7] | eliW[9] | eliW[11]) == 0);
  int shift = is64 ? 1 : 0;

  float bl[16], wl[16];
  *(float4*)(bl + 0)  = *(const float4*)(b1 + ql * 8);
  *(float4*)(bl + 4)  = *(const float4*)(b1 + ql * 8 + 4);
  *(float4*)(bl + 8)  = *(const float4*)(b1 + 128 + ql * 8);
  *(float4*)(bl + 12) = *(const float4*)(b1 + 128 + ql * 8 + 4);
  *(float4*)(wl + 0)  = *(const float4*)(W2 + ql * 8);
  *(float4*)(wl + 4)  = *(const float4*)(W2 + ql * 8 + 4);
  *(float4*)(wl + 8)  = *(const float4*)(W2 + 128 + ql * 8);
  *(float4*)(wl + 12) = *(const float4*)(W2 + 128 + ql * 8 + 4);
  float bias2 = b2[0];

  int qid = (blockIdx.x * blockDim.x + tid) >> 4;
  int nq = (gridDim.x * blockDim.x) >> 4;

#define DOT(UU, VV, SREG)                                                      \
  {                                                                            \
    float s_ = 0.f;                                                            \
    _Pragma("unroll")                                                          \
    for (int g = 0; g < 2; ++g)                                                \
      _Pragma("unroll")                                                        \
      for (int j = 0; j < 8; ++j) {                                            \
        float h = bf2f((unsigned short)UU[g][j]) +                             \
                  bf2f((unsigned short)VV[g][j]) + bl[g * 8 + j];              \
        s_ += fmaxf(h, 0.f) * wl[g * 8 + j];                                   \
      }                                                                        \
    _Pragma("unroll")                                                          \
    for (int off = 8; off; off >>= 1) s_ += __shfl_xor(s_, off, 64);           \
    SREG = s_;                                                                 \
  }

  for (int e = qid; e < E; e += 2 * nq) {
    int e1 = e + nq;
    bool has1 = e1 < E;
    int e1c = has1 ? e1 : e;
    int src0 = eliW[((size_t)e) << shift];
    int dst0 = eliW[((size_t)(E + e)) << shift];
    int src1 = eliW[((size_t)e1c) << shift];
    int dst1 = eliW[((size_t)(E + e1c)) << shift];

    const unsigned short* up0 = uv + (size_t)src0 * NOUTC;
    const unsigned short* vp0 = uv + (size_t)dst0 * NOUTC + DINC;
    const unsigned short* up1 = uv + (size_t)src1 * NOUTC;
    const unsigned short* vp1 = uv + (size_t)dst1 * NOUTC + DINC;

    short8 uu0[2], vv0[2], uu1[2], vv1[2];
    uu0[0] = *(const short8*)(up0 + ql * 8);
    uu0[1] = *(const short8*)(up0 + 128 + ql * 8);
    vv0[0] = *(const short8*)(vp0 + ql * 8);
    vv0[1] = *(const short8*)(vp0 + 128 + ql * 8);
    uu1[0] = *(const short8*)(up1 + ql * 8);
    uu1[1] = *(const short8*)(up1 + 128 + ql * 8);
    vv1[0] = *(const short8*)(vp1 + ql * 8);
    vv1[1] = *(const short8*)(vp1 + 128 + ql * 8);

    float s0, s1;
    DOT(uu0, vv0, s0);
    DOT(uu1, vv1, s1);
    if (ql == 0) {
      out[e] = s0 + bias2;
      if (has1) out[e1] = s1 + bias2;
    }
  }
#undef DOT
}

extern "C" void kernel_launch(void* const* d_in, const int* in_sizes, int n_in,
                              void* d_out, int out_size, void* d_ws, size_t ws_size,
                              hipStream_t stream) {
  const float* x   = (const float*)d_in[0];
  const int*   eli = (const int*)d_in[1];
  const float* W1  = (const float*)d_in[2];
  const float* b1  = (const float*)d_in[3];
  const float* W2  = (const float*)d_in[4];
  const float* b2  = (const float*)d_in[5];
  float* out = (float*)d_out;

  int Nn = in_sizes[0] / DINC;     // 100000
  int E  = in_sizes[1] / 2;        // 500000

  unsigned short* W1t = (unsigned short*)d_ws;              // 256 KB (frag-major)
  unsigned short* uv  = W1t + (size_t)NOUTC * DINC;         // ~102.4 MB

  w1t_kernel<<<64, 256, 0, stream>>>(W1, W1t);

  // 512 blocks = 2/CU persistent: 4 col-slices x 128 ranks.
  uv_gemm<<<512, 256, 0, stream>>>(x, W1t, uv, Nn);

  edge_kernel<<<2048, 256, 0, stream>>>(eli, uv, b1, W2, b2, out, E);
}

// Round 11
// 148.493 us; speedup vs baseline: 1.0841x; 1.0841x over previous
//
#include <hip/hip_runtime.h>
#include <hip/hip_bf16.h>

// out[e] = relu(concat(x[src],x[dst]) @ W1 + b1) @ W2 + b2
// Phase 0: xbf = bf16(x) in fragment-block order (granule g=(c16*8+kt)*64+lane
//   holds row c16*16+(lane&15), k = kt*32+(lane>>4)*8 .. +8).
// Phase 1: uv[n][0:256] = x[n]@W1[:256,:], uv[n][256:512] = x[n]@W1[256:,:] (bf16)
//   Stream GEMM: block owns 128 uv-cols; W1 slice in LDS frag-major (64 KB,
//   staged once, one barrier). Waves free-run over 32-ROW chunks: each B
//   fragment is ds_read ONCE and feeds 2 MFMAs (halves LDS issue/traffic).
//   A: bf16 from xbf, 16 dense 1KB loads/chunk, reg double-buffered (~215 VGPR).
// Phase 2: per-edge sum_k relu(uv[src][k]+uv[dst][256+k]+b1[k])*W2[k] + b2,
//   quarter-wave per edge, 2-edge unroll.

typedef short short8 __attribute__((ext_vector_type(8)));
typedef float f32x4 __attribute__((ext_vector_type(4)));

#define DINC 256
#define NOUTC 512

__device__ inline unsigned short f2bf(float f) {   // RNE (cold path)
  union { float f; unsigned u; } c; c.f = f;
  unsigned u = c.u;
  return (unsigned short)((u + 0x7FFFu + ((u >> 16) & 1u)) >> 16);
}
__device__ inline float bf2f(unsigned short h) {
  union { unsigned u; float f; } c; c.u = ((unsigned)h) << 16;
  return c.f;
}
__device__ inline unsigned short fbf(float f) {    // fuses to v_cvt_pk_bf16_f32
  union { __hip_bfloat16 h; unsigned short u; } c;
  c.h = __float2bfloat16(f);
  return c.u;
}

// W1t frag-major: t in [0,16384): bn=t>>12, kt=(t>>9)&7, nf=(t>>6)&7, lane=t&63
// -> col = bn*128+nf*16+(lane&15), k = kt*32+(lane>>4)*8+j.
__global__ void w1t_kernel(const float* __restrict__ W1, unsigned short* __restrict__ W1t) {
  int t = blockIdx.x * 256 + threadIdx.x;           // 0..16383
  int lane = t & 63, nf = (t >> 6) & 7, kt = (t >> 9) & 7, bn = t >> 12;
  int col = bn * 128 + nf * 16 + (lane & 15);
  int k0 = kt * 32 + (lane >> 4) * 8;
  int off = (col >= 256) ? 256 : 0;
  int cs = col & 255;
  short8 v;
#pragma unroll
  for (int j = 0; j < 8; ++j)
    v[j] = (short)f2bf(W1[(size_t)(k0 + j + off) * DINC + cs]);
  *(short8*)(W1t + (size_t)t * 8) = v;
}

// xbf producer (validated round 8): granule g: c16=g>>9, kt=(g>>6)&7, lane=g&63.
__global__ __launch_bounds__(256) void cvt_kernel(const float* __restrict__ x,
                                                  unsigned short* __restrict__ xbf,
                                                  int Nn) {
  int g = blockIdx.x * 256 + threadIdx.x;
  int lane = g & 63, kt = (g >> 6) & 7, c = g >> 9;
  int row = c * 16 + (lane & 15);
  if (row >= Nn) row = Nn - 1;
  int k0 = kt * 32 + (lane >> 4) * 8;
  const float4* xp = (const float4*)(x + (size_t)row * DINC + k0);
  float4 f0 = xp[0], f1 = xp[1];
  short8 v;
  v[0] = (short)fbf(f0.x); v[1] = (short)fbf(f0.y);
  v[2] = (short)fbf(f0.z); v[3] = (short)fbf(f0.w);
  v[4] = (short)fbf(f1.x); v[5] = (short)fbf(f1.y);
  v[6] = (short)fbf(f1.z); v[7] = (short)fbf(f1.w);
  *(short8*)(xbf + (size_t)g * 8) = v;
}

// 256 thr = 4 waves, 2 blocks/CU (LDS-limited), grid 512 persistent.
// Wave: 32-row x 128-col chunks; each B-fragment ds_read once -> 2 MFMAs.
__global__ __launch_bounds__(256, 1) void uv_gemm(const unsigned short* __restrict__ xbf,
                                                  const unsigned short* __restrict__ W1t,
                                                  unsigned short* __restrict__ uv,
                                                  int Nn) {
  __shared__ unsigned short Bs[128 * DINC];          // 64 KB frag-major

  // XCD remap: the 4 bn-slices of the same rank co-resident on one XCD L2.
  int L = (blockIdx.x & 7) * (gridDim.x >> 3) + (blockIdx.x >> 3);
  int bn = L & 3, rank = L >> 2;

  int tid = threadIdx.x, lane = tid & 63, w = tid >> 6;
  int lr = lane & 15, kg = lane >> 4;

  // ---- stage B slice once (linear 64 KB copy, frag-major source) ----
  {
    const char* bsrc = (const char*)W1t + (size_t)bn * 65536;
#pragma unroll
    for (int i = 0; i < 16; ++i) {
      int o = i * 4096 + w * 1024;                   // wave-uniform base
      __builtin_amdgcn_global_load_lds(
          (const __attribute__((address_space(1))) void*)(bsrc + o + lane * 16),
          (__attribute__((address_space(3))) void*)((char*)Bs + o), 16, 0, 0);
    }
  }
  __syncthreads();                                   // the only barrier

  int nch = (Nn + 31) >> 5;                          // 32-row chunks (3125)
  int stream = rank * 4 + w;                         // 0..511
  const int S = 512;
  const char* xb = (const char*)xbf;

  // 32-row chunk C = 16-row granule-chunks 2C (rows C*32+lr) and 2C+1 (+16).
#define LOADH(BUF, C)                                                          \
  {                                                                            \
    const char* p_ = xb + (size_t)(2 * (C)) * 8192 + lane * 16;                \
    _Pragma("unroll")                                                          \
    for (int kt = 0; kt < 8; ++kt) {                                           \
      BUF[kt]     = *(const short8*)(p_ + kt * 1024);                          \
      BUF[8 + kt] = *(const short8*)(p_ + 8192 + kt * 1024);                   \
    }                                                                          \
  }

#define CS(BUF, C)                                                             \
  {                                                                            \
    f32x4 acc0[8] = {}, acc1[8] = {};                                          \
    _Pragma("unroll")                                                          \
    for (int kt = 0; kt < 8; ++kt) {                                           \
      _Pragma("unroll")                                                        \
      for (int nf = 0; nf < 8; ++nf) {                                         \
        short8 bf_ = *(const short8*)((char*)Bs + ((kt * 8 + nf) * 64 + lane) * 16); \
        acc0[nf] = __builtin_amdgcn_mfma_f32_16x16x32_bf16(bf_, BUF[kt],       \
                                                           acc0[nf], 0, 0, 0); \
        acc1[nf] = __builtin_amdgcn_mfma_f32_16x16x32_bf16(bf_, BUF[8 + kt],   \
                                                           acc1[nf], 0, 0, 0); \
      }                                                                        \
    }                                                                          \
    int row0_ = (C) * 32 + lr;                                                 \
    if (row0_ < Nn) {                                                          \
      unsigned short* orow_ = uv + (size_t)row0_ * NOUTC + bn * 128 + kg * 4;  \
      _Pragma("unroll")                                                        \
      for (int nf = 0; nf < 8; ++nf) {                                         \
        ushort4 pk;                                                            \
        pk.x = fbf(acc0[nf][0]); pk.y = fbf(acc0[nf][1]);                      \
        pk.z = fbf(acc0[nf][2]); pk.w = fbf(acc0[nf][3]);                      \
        *(ushort4*)(orow_ + nf * 16) = pk;                                     \
      }                                                                        \
    }                                                                          \
    int row1_ = row0_ + 16;                                                    \
    if (row1_ < Nn) {                                                          \
      unsigned short* orow_ = uv + (size_t)row1_ * NOUTC + bn * 128 + kg * 4;  \
      _Pragma("unroll")                                                        \
      for (int nf = 0; nf < 8; ++nf) {                                         \
        ushort4 pk;                                                            \
        pk.x = fbf(acc1[nf][0]); pk.y = fbf(acc1[nf][1]);                      \
        pk.z = fbf(acc1[nf][2]); pk.w = fbf(acc1[nf][3]);                      \
        *(ushort4*)(orow_ + nf * 16) = pk;                                     \
      }                                                                        \
    }                                                                          \
  }

  short8 A0[16], A1[16];
  int c = stream;
  if (c < nch) {
    LOADH(A0, c);
    for (;;) {
      int c1 = c + S;
      if (c1 < nch) {
        LOADH(A1, c1);                               // next chunk under compute
        CS(A0, c);
        int c2 = c1 + S;
        if (c2 < nch) {
          LOADH(A0, c2);
          CS(A1, c1);
          c = c2;
        } else { CS(A1, c1); break; }
      } else { CS(A0, c); break; }
    }
  }
#undef LOADH
#undef CS
}

// Quarter-wave (16 lanes) per edge, 2-edge unroll: 8 gathers in flight.
__global__ __launch_bounds__(256) void edge_kernel(const int* __restrict__ eliW,
                                                   const unsigned short* __restrict__ uv,
                                                   const float* __restrict__ b1,
                                                   const float* __restrict__ W2,
                                                   const float* __restrict__ b2,
                                                   float* __restrict__ out, int E) {
  int tid = threadIdx.x;
  int ql = tid & 15;
  bool is64 = ((eliW[1] | eliW[3] | eliW[5] | eliW[7] | eliW[9] | eliW[11]) == 0);
  int shift = is64 ? 1 : 0;

  float bl[16], wl[16];
  *(float4*)(bl + 0)  = *(const float4*)(b1 + ql * 8);
  *(float4*)(bl + 4)  = *(const float4*)(b1 + ql * 8 + 4);
  *(float4*)(bl + 8)  = *(const float4*)(b1 + 128 + ql * 8);
  *(float4*)(bl + 12) = *(const float4*)(b1 + 128 + ql * 8 + 4);
  *(float4*)(wl + 0)  = *(const float4*)(W2 + ql * 8);
  *(float4*)(wl + 4)  = *(const float4*)(W2 + ql * 8 + 4);
  *(float4*)(wl + 8)  = *(const float4*)(W2 + 128 + ql * 8);
  *(float4*)(wl + 12) = *(const float4*)(W2 + 128 + ql * 8 + 4);
  float bias2 = b2[0];

  int qid = (blockIdx.x * blockDim.x + tid) >> 4;
  int nq = (gridDim.x * blockDim.x) >> 4;

#define DOT(UU, VV, SREG)                                                      \
  {                                                                            \
    float s_ = 0.f;                                                            \
    _Pragma("unroll")                                                          \
    for (int g = 0; g < 2; ++g)                                                \
      _Pragma("unroll")                                                        \
      for (int j = 0; j < 8; ++j) {                                            \
        float h = bf2f((unsigned short)UU[g][j]) +                             \
                  bf2f((unsigned short)VV[g][j]) + bl[g * 8 + j];              \
        s_ += fmaxf(h, 0.f) * wl[g * 8 + j];                                   \
      }                                                                        \
    _Pragma("unroll")                                                          \
    for (int off = 8; off; off >>= 1) s_ += __shfl_xor(s_, off, 64);           \
    SREG = s_;                                                                 \
  }

  for (int e = qid; e < E; e += 2 * nq) {
    int e1 = e + nq;
    bool has1 = e1 < E;
    int e1c = has1 ? e1 : e;
    int src0 = eliW[((size_t)e) << shift];
    int dst0 = eliW[((size_t)(E + e)) << shift];
    int src1 = eliW[((size_t)e1c) << shift];
    int dst1 = eliW[((size_t)(E + e1c)) << shift];

    const unsigned short* up0 = uv + (size_t)src0 * NOUTC;
    const unsigned short* vp0 = uv + (size_t)dst0 * NOUTC + DINC;
    const unsigned short* up1 = uv + (size_t)src1 * NOUTC;
    const unsigned short* vp1 = uv + (size_t)dst1 * NOUTC + DINC;

    short8 uu0[2], vv0[2], uu1[2], vv1[2];
    uu0[0] = *(const short8*)(up0 + ql * 8);
    uu0[1] = *(const short8*)(up0 + 128 + ql * 8);
    vv0[0] = *(const short8*)(vp0 + ql * 8);
    vv0[1] = *(const short8*)(vp0 + 128 + ql * 8);
    uu1[0] = *(const short8*)(up1 + ql * 8);
    uu1[1] = *(const short8*)(up1 + 128 + ql * 8);
    vv1[0] = *(const short8*)(vp1 + ql * 8);
    vv1[1] = *(const short8*)(vp1 + 128 + ql * 8);

    float s0, s1;
    DOT(uu0, vv0, s0);
    DOT(uu1, vv1, s1);
    if (ql == 0) {
      out[e] = s0 + bias2;
      if (has1) out[e1] = s1 + bias2;
    }
  }
#undef DOT
}

extern "C" void kernel_launch(void* const* d_in, const int* in_sizes, int n_in,
                              void* d_out, int out_size, void* d_ws, size_t ws_size,
                              hipStream_t stream) {
  const float* x   = (const float*)d_in[0];
  const int*   eli = (const int*)d_in[1];
  const float* W1  = (const float*)d_in[2];
  const float* b1  = (const float*)d_in[3];
  const float* W2  = (const float*)d_in[4];
  const float* b2  = (const float*)d_in[5];
  float* out = (float*)d_out;

  int Nn = in_sizes[0] / DINC;     // 100000
  int E  = in_sizes[1] / 2;        // 500000
  int nch16 = (Nn + 15) >> 4;      // 6250

  unsigned short* W1t = (unsigned short*)d_ws;              // 256 KB (frag-major)
  unsigned short* uv  = W1t + (size_t)NOUTC * DINC;         // ~102.4 MB
  unsigned short* xbf = uv + (size_t)Nn * NOUTC;            // ~51.2 MB (frag-block)

  w1t_kernel<<<64, 256, 0, stream>>>(W1, W1t);
  cvt_kernel<<<nch16 * 2, 256, 0, stream>>>(x, xbf, Nn);

  // 512 blocks = 2/CU persistent: 4 col-slices x 128 ranks.
  uv_gemm<<<512, 256, 0, stream>>>(xbf, W1t, uv, Nn);

  edge_kernel<<<2048, 256, 0, stream>>>(eli, uv, b1, W2, b2, out, E);
}